// Round 6
// baseline (14810.944 us; speedup 1.0000x reference)
//
#include <hip/hip_runtime.h>
#include <math.h>

#define HDIM 1024
#define BDIM 64
#define TDIM 512
#define KIN  128
#define NBLK 256
#define NTHR 1024
#define FRAME (HDIM * BDIM)   // halfs per ring frame
#define NGRP 8
#define GSZ  (NBLK / NGRP)    // 32

typedef _Float16 f16;
typedef __attribute__((ext_vector_type(2))) _Float16 f16x2;
typedef __attribute__((ext_vector_type(8))) _Float16 f16x8;
typedef __attribute__((ext_vector_type(4))) float f32x4;

#define MFMA16(a, b, c) __builtin_amdgcn_mfma_f32_16x16x32_f16((a), (b), (c), 0, 0, 0)

__device__ __forceinline__ float sigm(float x) { return 1.0f / (1.0f + expf(-x)); }

// ---------------------------------------------------------------------------
// Hierarchical split barrier. Layout per barrier (uints, base 4-byte aligned):
//   [grp*32]        : group arrival counters (8 lines, 128 B apart)
//   [256]           : root arrival counter
//   [288]           : root flag (completed epochs)
//   [320 + grp*32]  : per-group broadcast flags
// Arrival: 32-way same-line contention per group (parallel lines) + 8-way
// root — vs round 5's 256-way single line (~16 us serialized).
// Broadcast: 8 pollers on root flag, 31 per group flag.
// Epochs monotonic; arrive returns group-leadership for the matching wait.
// ---------------------------------------------------------------------------
__device__ __forceinline__ bool bar_arrive(unsigned* base, int grp, unsigned ep) {
    // caller guarantees a preceding __syncthreads (all waves' stores drained)
    __builtin_amdgcn_fence(__ATOMIC_RELEASE, "agent");   // L2 writeback
    unsigned o = __hip_atomic_fetch_add(base + grp * 32, 1u, __ATOMIC_RELAXED,
                                        __HIP_MEMORY_SCOPE_AGENT);
    bool lead = (o == ep * GSZ - 1u);
    if (lead) {
        unsigned r = __hip_atomic_fetch_add(base + 256, 1u, __ATOMIC_RELAXED,
                                            __HIP_MEMORY_SCOPE_AGENT);
        if (r == ep * NGRP - 1u)
            __hip_atomic_store(base + 288, ep, __ATOMIC_RELAXED,
                               __HIP_MEMORY_SCOPE_AGENT);
    }
    return lead;
}

__device__ __forceinline__ void bar_wait(unsigned* base, int grp, unsigned ep,
                                         bool lead) {
    if (lead) {
        while (__hip_atomic_load(base + 288, __ATOMIC_RELAXED,
                                 __HIP_MEMORY_SCOPE_AGENT) < ep)
            __builtin_amdgcn_s_sleep(1);
        __hip_atomic_store(base + 320 + grp * 32, ep, __ATOMIC_RELAXED,
                           __HIP_MEMORY_SCOPE_AGENT);
    } else {
        while (__hip_atomic_load(base + 320 + grp * 32, __ATOMIC_RELAXED,
                                 __HIP_MEMORY_SCOPE_AGENT) < ep)
            __builtin_amdgcn_s_sleep(1);
    }
    __builtin_amdgcn_fence(__ATOMIC_ACQUIRE, "agent");   // L1/L2 invalidate
}

// ---------------------------------------------------------------------------
// fp32 -> fp16 weight conversion (row-major layout preserved)
// ---------------------------------------------------------------------------
__global__ void cvt_w(const float* __restrict__ src, f16* __restrict__ dst, int n2) {
    int i = blockIdx.x * blockDim.x + threadIdx.x;
    if (i < n2) {
        float2 a = ((const float2*)src)[i];
        f16x2 o = {(f16)a.x, (f16)a.y};
        ((f16x2*)dst)[i] = o;
    }
}

// ---------------------------------------------------------------------------
// x[b][t][k] fp32 -> xP[t][b][k] fp16 (A-fragment friendly: k contiguous per b)
// ---------------------------------------------------------------------------
__global__ void cvt_x(const float* __restrict__ x, f16* __restrict__ xP) {
    int P = blockIdx.x * blockDim.x + threadIdx.x;    // pair index
    if (P >= TDIM * BDIM * (KIN / 2)) return;
    int kp = P & 63;
    int b  = (P >> 6) & 63;
    int t  = P >> 12;
    float2 v = ((const float2*)x)[((size_t)b * TDIM + t) * (KIN / 2) + kp];
    f16x2 o = {(f16)v.x, (f16)v.y};
    ((f16x2*)xP)[((size_t)t * BDIM + b) * (KIN / 2) + kp] = o;
}

// ---------------------------------------------------------------------------
// Fused 2-layer LSTM, MFMA, weights stationary in VGPRs. Compute body is
// identical to round 5; only the grid synchronization changed (hierarchical
// split barriers A=h1, B=h2 with overlapped completion).
// ---------------------------------------------------------------------------
__global__ void __launch_bounds__(NTHR, 4) lstm_fused(
    const f16* __restrict__ xP,
    const f16* __restrict__ Wc0, const f16* __restrict__ Wh0,
    const float* __restrict__ bih0, const float* __restrict__ bhh0,
    const f16* __restrict__ Wc1, const f16* __restrict__ Wh1,
    const float* __restrict__ bih1, const float* __restrict__ bhh1,
    f16* ring1, f16* ring2, unsigned* bar) {

    __shared__ float red[32 * 324 + 16];

    unsigned* barA = bar;
    unsigned* barB = bar + 1024;

    const int tid  = threadIdx.x;
    const int lane = tid & 63;
    const int w    = __builtin_amdgcn_readfirstlane(tid >> 6);   // 0..15
    const int iu4  = __builtin_amdgcn_readfirstlane((int)blockIdx.x * 4);
    const int grp  = __builtin_amdgcn_readfirstlane((int)blockIdx.x >> 5);

    const int n    = lane & 15;
    const int quad = lane >> 4;
    const int am   = lane & 15;
    const int wrow = iu4 + (n >> 2) + (n & 3) * HDIM;

    // ---- preload stationary weight fragments ----
    f16x8 B1x;
    f16x8 B1h[2], B2i[2], B2h[2];
    {
        const int kq = quad * 8;
        if (w < 4)
            B1x = *(const f16x8*)(Wc0 + (size_t)wrow * KIN + w * 32 + kq);
        #pragma unroll
        for (int j = 0; j < 2; ++j) {
            const int ks = (2 * w + j) * 32 + kq;
            B1h[j] = *(const f16x8*)(Wh0 + (size_t)wrow * HDIM + ks);
            B2i[j] = *(const f16x8*)(Wc1 + (size_t)wrow * HDIM + ks);
            B2h[j] = *(const f16x8*)(Wh1 + (size_t)wrow * HDIM + ks);
        }
    }

    float bias1[4], bias2[4];
    float c1 = 0.f, c2 = 0.f;
    const int il = w;
    const int m  = lane;
    if (w < 4) {
        const int i = iu4 + il;
        #pragma unroll
        for (int g = 0; g < 4; ++g) {
            bias1[g] = bih0[i + g * HDIM] + bhh0[i + g * HDIM];
            bias2[g] = bih1[i + g * HDIM] + bhh1[i + g * HDIM];
        }
        ring1[FRAME + (size_t)m * HDIM + i] = (f16)0.f;   // h^{(-1)} = 0
        ring2[FRAME + (size_t)m * HDIM + i] = (f16)0.f;
    }

    unsigned eA = 1, eB = 1;
    bool leadA = false, leadB = false;
    __syncthreads();
    if (tid == 0) {
        leadA = bar_arrive(barA, grp, 1);   // publish h1^{(-1)}
        leadB = bar_arrive(barB, grp, 1);   // publish h2^{(-1)}
    }

    for (int s = 0; s <= TDIM; ++s) {
        const f16* r1p = ring1 + (size_t)((s + 1) & 1) * FRAME;  // h1^{(s-1)}
        const f16* r2p = ring2 + (size_t)(s & 1) * FRAME;        // h2^{(s-2)}

        // ---- wait for h1^{(s-1)} (barrier A, epoch eA) ----
        if (tid == 0) bar_wait(barA, grp, eA, leadA);
        __syncthreads();

        // ---- A-fragments of h1^{(s-1)} (shared by phase1 and phase2) ----
        f16x8 A1[2][4];
        #pragma unroll
        for (int j = 0; j < 2; ++j) {
            const int ks = (2 * w + j) * 32 + quad * 8;
            #pragma unroll
            for (int mt = 0; mt < 4; ++mt)
                A1[j][mt] = *(const f16x8*)(r1p + (size_t)(mt * 16 + am) * HDIM + ks);
        }

        // ---- phase 1: layer1 step s ----
        f32x4 acc[4];
        #pragma unroll
        for (int mt = 0; mt < 4; ++mt) acc[mt] = (f32x4){0.f, 0.f, 0.f, 0.f};
        #pragma unroll
        for (int j = 0; j < 2; ++j)
            #pragma unroll
            for (int mt = 0; mt < 4; ++mt)
                acc[mt] = MFMA16(A1[j][mt], B1h[j], acc[mt]);
        if (w < 4) {
            const int ts = (s < TDIM) ? s : (TDIM - 1);
            const f16* xb = xP + (size_t)ts * BDIM * KIN;
            const int kx = w * 32 + quad * 8;
            #pragma unroll
            for (int mt = 0; mt < 4; ++mt) {
                f16x8 ax = *(const f16x8*)(xb + (size_t)(mt * 16 + am) * KIN + kx);
                acc[mt] = MFMA16(ax, B1x, acc[mt]);
            }
        }

        const int p = w & 7;
        if (w < 8) {
            #pragma unroll
            for (int mt = 0; mt < 4; ++mt)
                *(f32x4*)&red[(p * 4 + mt) * 324 + n * 20 + quad * 4] = acc[mt];
        }
        __syncthreads();
        if (w >= 8) {
            #pragma unroll
            for (int mt = 0; mt < 4; ++mt) {
                float* a = &red[(p * 4 + mt) * 324 + n * 20 + quad * 4];
                f32x4 v = *(f32x4*)a;
                *(f32x4*)a = v + acc[mt];
            }
        }
        __syncthreads();

        // ---- phase 2a MFMA (layer2 step s-1, Wih1 part — no new ring data) ----
        f32x4 acc2[4];
        #pragma unroll
        for (int mt = 0; mt < 4; ++mt) acc2[mt] = (f32x4){0.f, 0.f, 0.f, 0.f};
        #pragma unroll
        for (int j = 0; j < 2; ++j)
            #pragma unroll
            for (int mt = 0; mt < 4; ++mt)
                acc2[mt] = MFMA16(A1[j][mt], B2i[j], acc2[mt]);

        // ---- reduce1: gates -> activations -> h1 store (waves 0..3) ----
        if (w < 4 && s < TDIM) {
            const int mt = m >> 4, qm = m & 15;
            float g4[4];
            #pragma unroll
            for (int g = 0; g < 4; ++g) {
                float sum = bias1[g];
                #pragma unroll
                for (int pp = 0; pp < 8; ++pp)
                    sum += red[(pp * 4 + mt) * 324 + (il * 4 + g) * 20 + qm];
                g4[g] = sum;
            }
            float ig = sigm(g4[0]), fg = sigm(g4[1]);
            float gg = tanhf(g4[2]), og = sigm(g4[3]);
            c1 = fg * c1 + ig * gg;
            float h = og * tanhf(c1);
            ring1[(size_t)(s & 1) * FRAME + (size_t)m * HDIM + (iu4 + il)] = (f16)h;
        }
        __syncthreads();   // drains h1 stores; protects red

        // ---- publish h1^{(s)}; wait for h2^{(s-2)} ----
        if (tid == 0) {
            ++eA;
            leadA = bar_arrive(barA, grp, eA);
            bar_wait(barB, grp, eB, leadB);
        }
        __syncthreads();

        // ---- phase 2b: Whh1 part (reads r2p = h2^{(s-2)}) ----
        #pragma unroll
        for (int j = 0; j < 2; ++j) {
            const int ks = (2 * w + j) * 32 + quad * 8;
            #pragma unroll
            for (int mt = 0; mt < 4; ++mt) {
                f16x8 a2 = *(const f16x8*)(r2p + (size_t)(mt * 16 + am) * HDIM + ks);
                acc2[mt] = MFMA16(a2, B2h[j], acc2[mt]);
            }
        }

        if (w < 8) {
            #pragma unroll
            for (int mt = 0; mt < 4; ++mt)
                *(f32x4*)&red[(p * 4 + mt) * 324 + n * 20 + quad * 4] = acc2[mt];
        }
        __syncthreads();
        if (w >= 8) {
            #pragma unroll
            for (int mt = 0; mt < 4; ++mt) {
                float* a = &red[(p * 4 + mt) * 324 + n * 20 + quad * 4];
                f32x4 v = *(f32x4*)a;
                *(f32x4*)a = v + acc2[mt];
            }
        }
        __syncthreads();

        // ---- reduce2: layer2 activations -> h2 store ----
        if (w < 4 && s >= 1) {
            const int mt = m >> 4, qm = m & 15;
            float g4[4];
            #pragma unroll
            for (int g = 0; g < 4; ++g) {
                float sum = bias2[g];
                #pragma unroll
                for (int pp = 0; pp < 8; ++pp)
                    sum += red[(pp * 4 + mt) * 324 + (il * 4 + g) * 20 + qm];
                g4[g] = sum;
            }
            float ig = sigm(g4[0]), fg = sigm(g4[1]);
            float gg = tanhf(g4[2]), og = sigm(g4[3]);
            c2 = fg * c2 + ig * gg;
            float h = og * tanhf(c2);
            ring2[(size_t)((s + 1) & 1) * FRAME + (size_t)m * HDIM + (iu4 + il)] = (f16)h;
        }
        __syncthreads();   // drains h2 stores

        // ---- publish h2^{(s-1)} ----
        if (tid == 0) {
            ++eB;
            leadB = bar_arrive(barB, grp, eB);
        }
    }
    // final h2^{(511)} is in ring2 frame 1
}

// ---------------------------------------------------------------------------
// out[b] = dot(h2[b, :], fc_w) + fc_b.   h2 is [batch][H] fp16.
// ---------------------------------------------------------------------------
__global__ void fc_kernel(const f16* __restrict__ h2f,
                          const float* __restrict__ fcw,
                          const float* __restrict__ fcb,
                          float* __restrict__ out) {
    __shared__ float red[256];
    const int tid = threadIdx.x;
    const int b = tid >> 2, q = tid & 3;
    float s = 0.f;
    for (int i = q * (HDIM / 4); i < (q + 1) * (HDIM / 4); ++i)
        s = fmaf((float)h2f[(size_t)b * HDIM + i], fcw[i], s);
    red[tid] = s;
    __syncthreads();
    if (q == 0)
        out[b] = red[tid] + red[tid + 1] + red[tid + 2] + red[tid + 3] + fcb[0];
}

// ---------------------------------------------------------------------------
extern "C" void kernel_launch(void* const* d_in, const int* in_sizes, int n_in,
                              void* d_out, int out_size, void* d_ws, size_t ws_size,
                              hipStream_t stream) {
    const float* x    = (const float*)d_in[0];
    const float* Wih0 = (const float*)d_in[1];
    const float* Whh0 = (const float*)d_in[2];
    const float* bih0 = (const float*)d_in[3];
    const float* bhh0 = (const float*)d_in[4];
    const float* Wih1 = (const float*)d_in[5];
    const float* Whh1 = (const float*)d_in[6];
    const float* bih1 = (const float*)d_in[7];
    const float* bhh1 = (const float*)d_in[8];
    const float* fcw  = (const float*)d_in[9];
    const float* fcb  = (const float*)d_in[10];
    float* out = (float*)d_out;

    // workspace (halfs): xP | Wc0 | Wh0 | Wc1 | Wh1 | ring1 | ring2 | bar
    f16* xPd   = (f16*)d_ws;
    f16* Wc0   = xPd + (size_t)TDIM * BDIM * KIN;
    f16* Wh0   = Wc0 + (size_t)4 * HDIM * KIN;
    f16* Wc1   = Wh0 + (size_t)4 * HDIM * HDIM;
    f16* Wh1   = Wc1 + (size_t)4 * HDIM * HDIM;
    f16* ring1 = Wh1 + (size_t)4 * HDIM * HDIM;
    f16* ring2 = ring1 + 2 * FRAME;
    unsigned* bar = (unsigned*)(ring2 + 2 * FRAME);

    hipMemsetAsync(bar, 0, 8192, stream);   // both barrier trees = 0
    {
        int n2 = 4 * HDIM * KIN / 2;
        cvt_w<<<dim3((n2 + 255) / 256), dim3(256), 0, stream>>>(Wih0, Wc0, n2);
        n2 = 4 * HDIM * HDIM / 2;
        cvt_w<<<dim3((n2 + 255) / 256), dim3(256), 0, stream>>>(Whh0, Wh0, n2);
        cvt_w<<<dim3((n2 + 255) / 256), dim3(256), 0, stream>>>(Whh1, Wh1, n2);
        cvt_w<<<dim3((n2 + 255) / 256), dim3(256), 0, stream>>>(Wih1, Wc1, n2);
    }
    {
        int np = TDIM * BDIM * (KIN / 2);
        cvt_x<<<dim3((np + 255) / 256), dim3(256), 0, stream>>>(x, xPd);
    }

    void* args[12];
    args[0]  = (void*)&xPd;
    args[1]  = (void*)&Wc0;
    args[2]  = (void*)&Wh0;
    args[3]  = (void*)&bih0;
    args[4]  = (void*)&bhh0;
    args[5]  = (void*)&Wc1;
    args[6]  = (void*)&Wh1;
    args[7]  = (void*)&bih1;
    args[8]  = (void*)&bhh1;
    args[9]  = (void*)&ring1;
    args[10] = (void*)&ring2;
    args[11] = (void*)&bar;
    hipLaunchCooperativeKernel(reinterpret_cast<void*>(lstm_fused), dim3(NBLK), dim3(NTHR),
                               args, 0, stream);

    fc_kernel<<<dim3(1), dim3(256), 0, stream>>>(ring2 + FRAME, fcw, fcb, out);
}

// Round 7
// 7581.120 us; speedup vs baseline: 1.9537x; 1.9537x over previous
//
#include <hip/hip_runtime.h>
#include <math.h>

#define HDIM 1024
#define BDIM 64
#define TDIM 512
#define KIN  128
#define NBLK 256
#define NTHR 1024
#define FRAME (HDIM * BDIM)   // halfs per ring frame
#define NGRP 8
#define GSZ  (NBLK / NGRP)    // 32

typedef _Float16 f16;
typedef __attribute__((ext_vector_type(2))) _Float16 f16x2;
typedef __attribute__((ext_vector_type(8))) _Float16 f16x8;
typedef __attribute__((ext_vector_type(4))) float f32x4;

#define MFMA16(a, b, c) __builtin_amdgcn_mfma_f32_16x16x32_f16((a), (b), (c), 0, 0, 0)

__device__ __forceinline__ float sigm(float x) { return 1.0f / (1.0f + expf(-x)); }

// ---------------------------------------------------------------------------
// Coherence-point (L3) ring I/O — bypasses L1/L2 so cross-XCD data is seen
// without any cache-wide fence (buffer_wbl2/buffer_inv), which profiling
// showed costs ~10 us per barrier event.
// ---------------------------------------------------------------------------
__device__ __forceinline__ f16x8 ld_cg(const f16* p) {
    f16x8 r;
    asm volatile("global_load_dwordx4 %0, %1, off sc0 sc1"
                 : "=v"(r) : "v"(p) : "memory");
    return r;
}
// Pass-through waitcnt: consumers of r0..r7 data-depend on this asm's outputs,
// so nothing can be scheduled before the wait.
#define VM_WAIT8(r0, r1, r2, r3, r4, r5, r6, r7)                         \
    asm volatile("s_waitcnt vmcnt(0)"                                    \
                 : "+v"(r0), "+v"(r1), "+v"(r2), "+v"(r3),               \
                   "+v"(r4), "+v"(r5), "+v"(r6), "+v"(r7))

__device__ __forceinline__ void st_cg(f16* p, f16 v) {
    unsigned short u = __builtin_bit_cast(unsigned short, v);
    asm volatile("global_store_short %0, %1, off sc0 sc1"
                 :: "v"(p), "v"(u) : "memory");
}
#define VM_DRAIN() asm volatile("s_waitcnt vmcnt(0)" ::: "memory")

// ---------------------------------------------------------------------------
// Fence-free hierarchical grid barrier (arrive+wait fused). Layout (uints):
//   [grp*32]       group arrival counters (8 parallel 128B lines)
//   [256]          root arrival counter
//   [288]          root flag
//   [320+grp*32]   per-group broadcast flags
// Caller guarantees: per-wave vmcnt(0) drain of its sc0sc1 stores BEFORE the
// entry __syncthreads (store visible at L3 -> flag publish orders it).
// ---------------------------------------------------------------------------
__device__ __forceinline__ void grid_bar(unsigned* base, int grp, unsigned ep) {
    __syncthreads();
    if (threadIdx.x == 0) {
        unsigned o = __hip_atomic_fetch_add(base + grp * 32, 1u,
                                            __ATOMIC_RELAXED,
                                            __HIP_MEMORY_SCOPE_AGENT);
        if (o == ep * GSZ - 1u) {                       // group leader
            unsigned r = __hip_atomic_fetch_add(base + 256, 1u,
                                                __ATOMIC_RELAXED,
                                                __HIP_MEMORY_SCOPE_AGENT);
            if (r == ep * NGRP - 1u)
                __hip_atomic_store(base + 288, ep, __ATOMIC_RELAXED,
                                   __HIP_MEMORY_SCOPE_AGENT);
            while (__hip_atomic_load(base + 288, __ATOMIC_RELAXED,
                                     __HIP_MEMORY_SCOPE_AGENT) < ep)
                __builtin_amdgcn_s_sleep(1);
            __hip_atomic_store(base + 320 + grp * 32, ep, __ATOMIC_RELAXED,
                               __HIP_MEMORY_SCOPE_AGENT);
        } else {
            while (__hip_atomic_load(base + 320 + grp * 32, __ATOMIC_RELAXED,
                                     __HIP_MEMORY_SCOPE_AGENT) < ep)
                __builtin_amdgcn_s_sleep(1);
        }
    }
    __syncthreads();
}

// ---------------------------------------------------------------------------
// fp32 -> fp16 weight conversion (row-major layout preserved)
// ---------------------------------------------------------------------------
__global__ void cvt_w(const float* __restrict__ src, f16* __restrict__ dst, int n2) {
    int i = blockIdx.x * blockDim.x + threadIdx.x;
    if (i < n2) {
        float2 a = ((const float2*)src)[i];
        f16x2 o = {(f16)a.x, (f16)a.y};
        ((f16x2*)dst)[i] = o;
    }
}

// ---------------------------------------------------------------------------
// x[b][t][k] fp32 -> xP[t][b][k] fp16 (A-fragment friendly: k contiguous per b)
// ---------------------------------------------------------------------------
__global__ void cvt_x(const float* __restrict__ x, f16* __restrict__ xP) {
    int P = blockIdx.x * blockDim.x + threadIdx.x;    // pair index
    if (P >= TDIM * BDIM * (KIN / 2)) return;
    int kp = P & 63;
    int b  = (P >> 6) & 63;
    int t  = P >> 12;
    float2 v = ((const float2*)x)[((size_t)b * TDIM + t) * (KIN / 2) + kp];
    f16x2 o = {(f16)v.x, (f16)v.y};
    ((f16x2*)xP)[((size_t)t * BDIM + b) * (KIN / 2) + kp] = o;
}

// ---------------------------------------------------------------------------
// Fused 2-layer LSTM, MFMA, weights stationary in VGPRs (r5 compute body).
// Ring data via sc0sc1 L3-coherent I/O; single fence-free tree barrier/step.
// ---------------------------------------------------------------------------
__global__ void __launch_bounds__(NTHR, 4) lstm_fused(
    const f16* __restrict__ xP,
    const f16* __restrict__ Wc0, const f16* __restrict__ Wh0,
    const float* __restrict__ bih0, const float* __restrict__ bhh0,
    const f16* __restrict__ Wc1, const f16* __restrict__ Wh1,
    const float* __restrict__ bih1, const float* __restrict__ bhh1,
    f16* ring1, f16* ring2, unsigned* bar) {

    __shared__ float red[32 * 324 + 16];

    const int tid  = threadIdx.x;
    const int lane = tid & 63;
    const int w    = __builtin_amdgcn_readfirstlane(tid >> 6);   // 0..15
    const int iu4  = __builtin_amdgcn_readfirstlane((int)blockIdx.x * 4);
    const int grp  = __builtin_amdgcn_readfirstlane((int)blockIdx.x >> 5);

    const int n    = lane & 15;
    const int quad = lane >> 4;
    const int am   = lane & 15;
    const int wrow = iu4 + (n >> 2) + (n & 3) * HDIM;

    // ---- preload stationary weight fragments ----
    f16x8 B1x;
    f16x8 B1h[2], B2i[2], B2h[2];
    {
        const int kq = quad * 8;
        if (w < 4)
            B1x = *(const f16x8*)(Wc0 + (size_t)wrow * KIN + w * 32 + kq);
        #pragma unroll
        for (int j = 0; j < 2; ++j) {
            const int ks = (2 * w + j) * 32 + kq;
            B1h[j] = *(const f16x8*)(Wh0 + (size_t)wrow * HDIM + ks);
            B2i[j] = *(const f16x8*)(Wc1 + (size_t)wrow * HDIM + ks);
            B2h[j] = *(const f16x8*)(Wh1 + (size_t)wrow * HDIM + ks);
        }
    }

    float bias1[4], bias2[4];
    float c1 = 0.f, c2 = 0.f;
    const int il = w;
    const int m  = lane;
    if (w < 4) {
        const int i = iu4 + il;
        #pragma unroll
        for (int g = 0; g < 4; ++g) {
            bias1[g] = bih0[i + g * HDIM] + bhh0[i + g * HDIM];
            bias2[g] = bih1[i + g * HDIM] + bhh1[i + g * HDIM];
        }
        st_cg(ring1 + FRAME + (size_t)m * HDIM + i, (f16)0.f);   // h^{(-1)}=0
        st_cg(ring2 + FRAME + (size_t)m * HDIM + i, (f16)0.f);
        VM_DRAIN();
    }

    unsigned ep = 1;
    grid_bar(bar, grp, ep++);

    for (int s = 0; s <= TDIM; ++s) {
        const f16* r1p = ring1 + (size_t)((s + 1) & 1) * FRAME;  // h1^{(s-1)}
        const f16* r2p = ring2 + (size_t)(s & 1) * FRAME;        // h2^{(s-2)}
        const int ks0 = (2 * w + 0) * 32 + quad * 8;
        const int ks1 = (2 * w + 1) * 32 + quad * 8;

        // ---- A-fragments of h1^{(s-1)} (L3-coherent loads) ----
        f16x8 A1[2][4];
        #pragma unroll
        for (int mt = 0; mt < 4; ++mt) {
            A1[0][mt] = ld_cg(r1p + (size_t)(mt * 16 + am) * HDIM + ks0);
            A1[1][mt] = ld_cg(r1p + (size_t)(mt * 16 + am) * HDIM + ks1);
        }
        VM_WAIT8(A1[0][0], A1[0][1], A1[0][2], A1[0][3],
                 A1[1][0], A1[1][1], A1[1][2], A1[1][3]);

        // ---- phase 1: layer1 step s ----
        f32x4 acc[4];
        #pragma unroll
        for (int mt = 0; mt < 4; ++mt) acc[mt] = (f32x4){0.f, 0.f, 0.f, 0.f};
        #pragma unroll
        for (int j = 0; j < 2; ++j)
            #pragma unroll
            for (int mt = 0; mt < 4; ++mt)
                acc[mt] = MFMA16(A1[j][mt], B1h[j], acc[mt]);
        if (w < 4) {
            const int ts = (s < TDIM) ? s : (TDIM - 1);
            const f16* xb = xP + (size_t)ts * BDIM * KIN;
            const int kx = w * 32 + quad * 8;
            #pragma unroll
            for (int mt = 0; mt < 4; ++mt) {
                f16x8 ax = *(const f16x8*)(xb + (size_t)(mt * 16 + am) * KIN + kx);
                acc[mt] = MFMA16(ax, B1x, acc[mt]);
            }
        }

        // ---- issue h2^{(s-2)} fragment loads early (hide L3 latency) ----
        f16x8 A2[2][4];
        #pragma unroll
        for (int mt = 0; mt < 4; ++mt) {
            A2[0][mt] = ld_cg(r2p + (size_t)(mt * 16 + am) * HDIM + ks0);
            A2[1][mt] = ld_cg(r2p + (size_t)(mt * 16 + am) * HDIM + ks1);
        }

        const int p = w & 7;
        if (w < 8) {
            #pragma unroll
            for (int mt = 0; mt < 4; ++mt)
                *(f32x4*)&red[(p * 4 + mt) * 324 + n * 20 + quad * 4] = acc[mt];
        }
        __syncthreads();
        if (w >= 8) {
            #pragma unroll
            for (int mt = 0; mt < 4; ++mt) {
                float* a = &red[(p * 4 + mt) * 324 + n * 20 + quad * 4];
                f32x4 v = *(f32x4*)a;
                *(f32x4*)a = v + acc[mt];
            }
        }
        __syncthreads();

        // ---- phase 2: layer2 step s-1 ----
        f32x4 acc2[4];
        #pragma unroll
        for (int mt = 0; mt < 4; ++mt) acc2[mt] = (f32x4){0.f, 0.f, 0.f, 0.f};
        #pragma unroll
        for (int j = 0; j < 2; ++j)
            #pragma unroll
            for (int mt = 0; mt < 4; ++mt)
                acc2[mt] = MFMA16(A1[j][mt], B2i[j], acc2[mt]);
        VM_WAIT8(A2[0][0], A2[0][1], A2[0][2], A2[0][3],
                 A2[1][0], A2[1][1], A2[1][2], A2[1][3]);
        #pragma unroll
        for (int j = 0; j < 2; ++j)
            #pragma unroll
            for (int mt = 0; mt < 4; ++mt)
                acc2[mt] = MFMA16(A2[j][mt], B2h[j], acc2[mt]);

        // ---- reduce1: gates -> activations -> h1 store (waves 0..3) ----
        if (w < 4 && s < TDIM) {
            const int mt = m >> 4, qm = m & 15;
            float g4[4];
            #pragma unroll
            for (int g = 0; g < 4; ++g) {
                float sum = bias1[g];
                #pragma unroll
                for (int pp = 0; pp < 8; ++pp)
                    sum += red[(pp * 4 + mt) * 324 + (il * 4 + g) * 20 + qm];
                g4[g] = sum;
            }
            float ig = sigm(g4[0]), fg = sigm(g4[1]);
            float gg = tanhf(g4[2]), og = sigm(g4[3]);
            c1 = fg * c1 + ig * gg;
            float h = og * tanhf(c1);
            st_cg(ring1 + (size_t)(s & 1) * FRAME + (size_t)m * HDIM + (iu4 + il),
                  (f16)h);
        }
        __syncthreads();   // reduce1 readers done; red reusable

        if (w < 8) {
            #pragma unroll
            for (int mt = 0; mt < 4; ++mt)
                *(f32x4*)&red[(p * 4 + mt) * 324 + n * 20 + quad * 4] = acc2[mt];
        }
        __syncthreads();
        if (w >= 8) {
            #pragma unroll
            for (int mt = 0; mt < 4; ++mt) {
                float* a = &red[(p * 4 + mt) * 324 + n * 20 + quad * 4];
                f32x4 v = *(f32x4*)a;
                *(f32x4*)a = v + acc2[mt];
            }
        }
        __syncthreads();

        // ---- reduce2: layer2 activations -> h2 store ----
        if (w < 4 && s >= 1) {
            const int mt = m >> 4, qm = m & 15;
            float g4[4];
            #pragma unroll
            for (int g = 0; g < 4; ++g) {
                float sum = bias2[g];
                #pragma unroll
                for (int pp = 0; pp < 8; ++pp)
                    sum += red[(pp * 4 + mt) * 324 + (il * 4 + g) * 20 + qm];
                g4[g] = sum;
            }
            float ig = sigm(g4[0]), fg = sigm(g4[1]);
            float gg = tanhf(g4[2]), og = sigm(g4[3]);
            c2 = fg * c2 + ig * gg;
            float h = og * tanhf(c2);
            st_cg(ring2 + (size_t)((s + 1) & 1) * FRAME + (size_t)m * HDIM + (iu4 + il),
                  (f16)h);
        }
        if (w < 4) VM_DRAIN();   // h1+h2 stores visible at L3 before arrival

        grid_bar(bar, grp, ep++);
    }
    // final h2^{(511)} is in ring2 frame 1
}

// ---------------------------------------------------------------------------
// out[b] = dot(h2[b, :], fc_w) + fc_b.   h2 is [batch][H] fp16.
// ---------------------------------------------------------------------------
__global__ void fc_kernel(const f16* __restrict__ h2f,
                          const float* __restrict__ fcw,
                          const float* __restrict__ fcb,
                          float* __restrict__ out) {
    __shared__ float red[256];
    const int tid = threadIdx.x;
    const int b = tid >> 2, q = tid & 3;
    float s = 0.f;
    for (int i = q * (HDIM / 4); i < (q + 1) * (HDIM / 4); ++i)
        s = fmaf((float)h2f[(size_t)b * HDIM + i], fcw[i], s);
    red[tid] = s;
    __syncthreads();
    if (q == 0)
        out[b] = red[tid] + red[tid + 1] + red[tid + 2] + red[tid + 3] + fcb[0];
}

// ---------------------------------------------------------------------------
extern "C" void kernel_launch(void* const* d_in, const int* in_sizes, int n_in,
                              void* d_out, int out_size, void* d_ws, size_t ws_size,
                              hipStream_t stream) {
    const float* x    = (const float*)d_in[0];
    const float* Wih0 = (const float*)d_in[1];
    const float* Whh0 = (const float*)d_in[2];
    const float* bih0 = (const float*)d_in[3];
    const float* bhh0 = (const float*)d_in[4];
    const float* Wih1 = (const float*)d_in[5];
    const float* Whh1 = (const float*)d_in[6];
    const float* bih1 = (const float*)d_in[7];
    const float* bhh1 = (const float*)d_in[8];
    const float* fcw  = (const float*)d_in[9];
    const float* fcb  = (const float*)d_in[10];
    float* out = (float*)d_out;

    // workspace (halfs): xP | Wc0 | Wh0 | Wc1 | Wh1 | ring1 | ring2 | bar
    f16* xPd   = (f16*)d_ws;
    f16* Wc0   = xPd + (size_t)TDIM * BDIM * KIN;
    f16* Wh0   = Wc0 + (size_t)4 * HDIM * KIN;
    f16* Wc1   = Wh0 + (size_t)4 * HDIM * HDIM;
    f16* Wh1   = Wc1 + (size_t)4 * HDIM * HDIM;
    f16* ring1 = Wh1 + (size_t)4 * HDIM * HDIM;
    f16* ring2 = ring1 + 2 * FRAME;
    unsigned* bar = (unsigned*)(ring2 + 2 * FRAME);

    hipMemsetAsync(bar, 0, 4096, stream);
    {
        int n2 = 4 * HDIM * KIN / 2;
        cvt_w<<<dim3((n2 + 255) / 256), dim3(256), 0, stream>>>(Wih0, Wc0, n2);
        n2 = 4 * HDIM * HDIM / 2;
        cvt_w<<<dim3((n2 + 255) / 256), dim3(256), 0, stream>>>(Whh0, Wh0, n2);
        cvt_w<<<dim3((n2 + 255) / 256), dim3(256), 0, stream>>>(Whh1, Wh1, n2);
        cvt_w<<<dim3((n2 + 255) / 256), dim3(256), 0, stream>>>(Wih1, Wc1, n2);
    }
    {
        int np = TDIM * BDIM * (KIN / 2);
        cvt_x<<<dim3((np + 255) / 256), dim3(256), 0, stream>>>(x, xPd);
    }

    void* args[12];
    args[0]  = (void*)&xPd;
    args[1]  = (void*)&Wc0;
    args[2]  = (void*)&Wh0;
    args[3]  = (void*)&bih0;
    args[4]  = (void*)&bhh0;
    args[5]  = (void*)&Wc1;
    args[6]  = (void*)&Wh1;
    args[7]  = (void*)&bih1;
    args[8]  = (void*)&bhh1;
    args[9]  = (void*)&ring1;
    args[10] = (void*)&ring2;
    args[11] = (void*)&bar;
    hipLaunchCooperativeKernel(reinterpret_cast<void*>(lstm_fused), dim3(NBLK), dim3(NTHR),
                               args, 0, stream);

    fc_kernel<<<dim3(1), dim3(256), 0, stream>>>(ring2 + FRAME, fcw, fcb, out);
}